// Round 1
// baseline (104.234 us; speedup 1.0000x reference)
//
#include <hip/hip_runtime.h>
#include <hip/hip_bf16.h>

// Chamfer-with-normals, B=8, C=6 (3 pos + 3 nrm), N=4096, fp32.
// d[i][j] = |ap_i|^2 + |bp_j|^2 - 2 ap_i.bp_j + W*(1 - bn_i.an_j)
// (normals are cross-indexed in the reference: row i uses b's normal, col j uses a's).
// Symmetric formulation: P_i=(ap_i, bn_i), Q_j=(bp_j, an_j); both chamfer
// directions are the same kernel with a/b swapped (dir = blockIdx.z).
//
// Main kernel: each thread holds R=8 rows' combined vectors r=(-2*pos, -W*nrm)
// in registers; col chunk (TJ=256) staged in LDS as AoS-8 (broadcast b128 reads).
// Inner loop: 7 VALU/pair (fma+5fmac+min); row bias |pos_i|^2 deferred to reduce.

constexpr int   NPTS  = 4096;
constexpr int   CPB   = 6;
constexpr int   BATCH = 8;
constexpr float W     = 0.001f;

template<int CHUNKS>
__global__ __launch_bounds__(256) void chamfer_min_kernel(
    const float* __restrict__ A, const float* __restrict__ B,
    float* __restrict__ partial)
{
    constexpr int TJ = NPTS / CHUNKS;
    const int dir   = blockIdx.z;
    const int batch = blockIdx.y;
    const int chunk = blockIdx.x % CHUNKS;
    const int rb    = blockIdx.x / CHUNKS;   // row block (2048 rows each)
    const float* rowPos = dir ? B : A;
    const float* rowNrm = dir ? A : B;
    const float* colPos = dir ? A : B;
    const float* colNrm = dir ? B : A;
    const int bb = batch * CPB * NPTS;
    const int tid = threadIdx.x;

    __shared__ float cols[TJ][8];
    for (int j = tid; j < TJ; j += 256) {
        int cj = chunk * TJ + j;
        float qx = colPos[bb + 0*NPTS + cj];
        float qy = colPos[bb + 1*NPTS + cj];
        float qz = colPos[bb + 2*NPTS + cj];
        float nx = colNrm[bb + 3*NPTS + cj];
        float ny = colNrm[bb + 4*NPTS + cj];
        float nz = colNrm[bb + 5*NPTS + cj];
        cols[j][0] = qx; cols[j][1] = qy; cols[j][2] = qz;
        cols[j][3] = nx; cols[j][4] = ny; cols[j][5] = nz;
        cols[j][6] = fmaf(qx, qx, fmaf(qy, qy, qz*qz)) + W;  // col bias (+W once)
        cols[j][7] = 0.f;
    }
    __syncthreads();

    float r[8][6];
    float m[8];
    const int rowBase = rb * 2048;
#pragma unroll
    for (int k = 0; k < 8; ++k) {
        int row = rowBase + k*256 + tid;      // strided: coalesced channel loads
        r[k][0] = -2.f * rowPos[bb + 0*NPTS + row];
        r[k][1] = -2.f * rowPos[bb + 1*NPTS + row];
        r[k][2] = -2.f * rowPos[bb + 2*NPTS + row];
        r[k][3] = -W   * rowNrm[bb + 3*NPTS + row];
        r[k][4] = -W   * rowNrm[bb + 4*NPTS + row];
        r[k][5] = -W   * rowNrm[bb + 5*NPTS + row];
        m[k] = 3.4e38f;
    }

#pragma unroll 2
    for (int jj = 0; jj < TJ; ++jj) {
        const float4 c0 = *reinterpret_cast<const float4*>(&cols[jj][0]); // qx qy qz nx
        const float4 c1 = *reinterpret_cast<const float4*>(&cols[jj][4]); // ny nz bias pad
#pragma unroll
        for (int k = 0; k < 8; ++k) {
            float acc = fmaf(r[k][0], c0.x, c1.z);
            acc = fmaf(r[k][1], c0.y, acc);
            acc = fmaf(r[k][2], c0.z, acc);
            acc = fmaf(r[k][3], c0.w, acc);
            acc = fmaf(r[k][4], c1.x, acc);
            acc = fmaf(r[k][5], c1.y, acc);
            m[k] = fminf(m[k], acc);
        }
    }

    float* p = partial + ((size_t)(dir*BATCH + batch)*CHUNKS + chunk)*NPTS;
#pragma unroll
    for (int k = 0; k < 8; ++k)
        p[rowBase + k*256 + tid] = m[k];
}

template<int CHUNKS>
__global__ __launch_bounds__(256) void chamfer_reduce_kernel(
    const float* __restrict__ A, const float* __restrict__ B,
    const float* __restrict__ partial, float* __restrict__ out)
{
    const int dir   = blockIdx.z;
    const int batch = blockIdx.y;
    const int row   = blockIdx.x * 256 + threadIdx.x;
    const float* rowPos = dir ? B : A;
    const int bb = batch * CPB * NPTS;
    const float* p = partial + (size_t)(dir*BATCH + batch)*CHUNKS*NPTS;

    float m = 3.4e38f;
#pragma unroll
    for (int c = 0; c < CHUNKS; ++c)
        m = fminf(m, p[c*NPTS + row]);

    float px = rowPos[bb + 0*NPTS + row];
    float py = rowPos[bb + 1*NPTS + row];
    float pz = rowPos[bb + 2*NPTS + row];
    float v = m + fmaf(px, px, fmaf(py, py, pz*pz));  // add deferred row bias

    for (int off = 32; off; off >>= 1)
        v += __shfl_down(v, off, 64);
    __shared__ float sred[4];
    if ((threadIdx.x & 63) == 0) sred[threadIdx.x >> 6] = v;
    __syncthreads();
    if (threadIdx.x == 0)
        atomicAdd(out, (sred[0] + sred[1] + sred[2] + sred[3]) * 0.125f); // /B
}

__global__ void zero_out_kernel(float* out) { out[0] = 0.f; }

extern "C" void kernel_launch(void* const* d_in, const int* in_sizes, int n_in,
                              void* d_out, int out_size, void* d_ws, size_t ws_size,
                              hipStream_t stream) {
    const float* A = (const float*)d_in[0];
    const float* B = (const float*)d_in[1];
    float* out     = (float*)d_out;
    float* partial = (float*)d_ws;

    zero_out_kernel<<<1, 1, 0, stream>>>(out);

    const size_t need16 = (size_t)2 * BATCH * 16 * NPTS * sizeof(float); // 4 MB
    if (ws_size >= need16) {
        chamfer_min_kernel<16><<<dim3(2*16, BATCH, 2), 256, 0, stream>>>(A, B, partial);
        chamfer_reduce_kernel<16><<<dim3(NPTS/256, BATCH, 2), 256, 0, stream>>>(A, B, partial, out);
    } else {
        chamfer_min_kernel<8><<<dim3(2*8, BATCH, 2), 256, 0, stream>>>(A, B, partial);
        chamfer_reduce_kernel<8><<<dim3(NPTS/256, BATCH, 2), 256, 0, stream>>>(A, B, partial, out);
    }
}